// Round 2
// baseline (344.433 us; speedup 1.0000x reference)
//
#include <hip/hip_runtime.h>
#include <hip/hip_bf16.h>
#include <cstdint>

// ---------------------------------------------------------------------------
// WindowAttention fused: one block (512 thr) per window (B=2048).
//   phase 0: X (64x192 fp32) -> LDS bf16
//   phase 1: QKV GEMM. Weight B-frags loaded global->regs (18 dwordx4/chunk),
//            NO barriers in K-loop. Epilogue writes Q,K (row-major, pad 40)
//            and V^T (pad 72) straight into LDS.
//   phase 2: attention, 24 tasks (6 heads x 4 row-tiles) over 8 waves.
//            softmax fp32 in regs (16-lane shfl groups match C-frag rows),
//            P via per-wave private LDS slice (same-wave RAW, no barrier),
//            output bf16 into the dead X LDS region (Xa).
//   phase 3: proj GEMM (B-frags global->regs), fp32 out + bias.
// 3 __syncthreads per block total. LDS 130 KB -> 1 block/CU, 2 waves/SIMD.
// ---------------------------------------------------------------------------

#define NTOK 64
#define NH 6
#define HD 32
#define WDIM 192
#define SCALE 0.17677669529663689f

typedef __bf16 bf16x8 __attribute__((ext_vector_type(8)));
typedef float f32x4 __attribute__((ext_vector_type(4)));

__device__ inline unsigned short f2bf(float f) {
    union { float f; unsigned u; } v; v.f = f;
    unsigned r = v.u + 0x7fff + ((v.u >> 16) & 1);   // RNE
    return (unsigned short)(r >> 16);
}

// ---------------------------------------------------------------------------
// K0: weight transpose/cast + combined bias table
// wqkv_t[n][k] (576x192 bf16), wproj_t[n][k] (192x192 bf16),
// comb[w][h][r][c] = rpbt[relidx(r,c)][h] + mask[w][r][c]
// ---------------------------------------------------------------------------
__global__ __launch_bounds__(256) void prep_kernel(
    const float* __restrict__ w_qkv, const float* __restrict__ w_proj,
    const float* __restrict__ rpbt, const float* __restrict__ mask,
    unsigned short* __restrict__ wqkv_t, unsigned short* __restrict__ wproj_t,
    float* __restrict__ comb) {
    int idx = blockIdx.x * 256 + threadIdx.x;
    if (idx < 576 * 192) {
        int n = idx / 192, k = idx % 192;
        wqkv_t[idx] = f2bf(w_qkv[k * 576 + n]);
        return;
    }
    int i2 = idx - 576 * 192;
    if (i2 < 192 * 192) {
        int n = i2 / 192, k = i2 % 192;
        wproj_t[i2] = f2bf(w_proj[k * 192 + n]);
        return;
    }
    int i3 = i2 - 192 * 192;
    if (i3 < 64 * NH * NTOK * NTOK) {
        int c = i3 & 63, r = (i3 >> 6) & 63;
        int h = (i3 >> 12) % NH;
        int w = i3 / (NH * 4096);
        int rr = (r >> 3) - (c >> 3) + 7;
        int cc = (r & 7) - (c & 7) + 7;
        comb[i3] = rpbt[(rr * 15 + cc) * NH + h] + mask[w * 4096 + r * 64 + c];
    }
}

// LDS row strides (shorts): all multiples of 8 -> 16B-aligned b128 reads,
// bank aliasing <= 2-way (free per m136).
#define LXP 200   // lx / Xa rows (192 cols used)
#define LQP 40    // lq/lk rows (32 cols used)
#define LVP 72    // lvt rows (64 cols used)
#define LPP 72    // P rows (64 cols used)

__global__ __launch_bounds__(512, 2) void fused_kernel(
    const float* __restrict__ X,
    const unsigned short* __restrict__ Wqkv, const float* __restrict__ b_qkv,
    const unsigned short* __restrict__ Wproj, const float* __restrict__ b_proj,
    const float* __restrict__ comb, float* __restrict__ out) {
    __shared__ unsigned short lx[64 * LXP];          // 25.6 KB  X then Xa
    __shared__ unsigned short lq[NH * 64 * LQP];     // 30.7 KB
    __shared__ unsigned short lk[NH * 64 * LQP];     // 30.7 KB
    __shared__ unsigned short lvt[NH * 32 * LVP];    // 27.6 KB  V transposed
    __shared__ unsigned short lp[8 * 16 * LPP];      // 18.4 KB  per-wave P

    const int tid = threadIdx.x;
    const int bwin = blockIdx.x;
    const int wave = tid >> 6, lane = tid & 63;
    const int l15 = lane & 15, quad = lane >> 4;

    // ---- phase 0: stage X (fp32 -> bf16) ----
    const float4* xg = (const float4*)(X + (size_t)bwin * NTOK * WDIM);
    #pragma unroll
    for (int i = 0; i < 6; i++) {
        int e4 = tid + i * 512;                  // 3072 float4
        int row = e4 / 48, c4 = e4 % 48;
        float4 v = xg[e4];
        union { unsigned short s[4]; uint2 u; } pk;
        pk.s[0] = f2bf(v.x); pk.s[1] = f2bf(v.y);
        pk.s[2] = f2bf(v.z); pk.s[3] = f2bf(v.w);
        *(uint2*)&lx[row * LXP + c4 * 4] = pk.u;
    }
    __syncthreads();

    // ---- phase 1: QKV GEMM ----
    // wave -> m-half mh (rows [32mh,32mh+32)), n-base (wave&3)*48 (3 n-tiles)
    const int mh = wave >> 2;
    const int nbase = (wave & 3) * 48;

    #pragma unroll
    for (int chunk = 0; chunk < 3; chunk++) {
        // B-fragments: 18 independent global_load_dwordx4 from L2-resident W
        bf16x8 bfr[3][6];
        #pragma unroll
        for (int nt = 0; nt < 3; nt++)
            #pragma unroll
            for (int ks = 0; ks < 6; ks++)
                bfr[nt][ks] = *(const bf16x8*)&Wqkv[
                    ((size_t)chunk * 192 + nbase + nt * 16 + l15) * 192 + ks * 32 + quad * 8];

        f32x4 acc[2][3];
        #pragma unroll
        for (int mt = 0; mt < 2; mt++)
            #pragma unroll
            for (int nt = 0; nt < 3; nt++)
                acc[mt][nt] = (f32x4){0.f, 0.f, 0.f, 0.f};

        #pragma unroll
        for (int ks = 0; ks < 6; ks++) {
            bf16x8 af[2];
            af[0] = *(const bf16x8*)&lx[(mh * 32 + l15) * LXP + ks * 32 + quad * 8];
            af[1] = *(const bf16x8*)&lx[(mh * 32 + 16 + l15) * LXP + ks * 32 + quad * 8];
            #pragma unroll
            for (int mt = 0; mt < 2; mt++)
                #pragma unroll
                for (int nt = 0; nt < 3; nt++)
                    acc[mt][nt] = __builtin_amdgcn_mfma_f32_16x16x32_bf16(
                        af[mt], bfr[nt][ks], acc[mt][nt], 0, 0, 0);
        }

        // epilogue: C/D layout col=lane&15, row=quad*4+reg
        #pragma unroll
        for (int nt = 0; nt < 3; nt++) {
            int cw = nbase + nt * 16 + l15;              // 0..191
            float bias = b_qkv[chunk * 192 + cw];
            int h = cw >> 5, d = cw & 31;
            #pragma unroll
            for (int mt = 0; mt < 2; mt++)
                #pragma unroll
                for (int r = 0; r < 4; r++) {
                    int t = mh * 32 + mt * 16 + quad * 4 + r;
                    unsigned short val = f2bf(acc[mt][nt][r] + bias);
                    if (chunk == 0)      lq[(h * 64 + t) * LQP + d] = val;
                    else if (chunk == 1) lk[(h * 64 + t) * LQP + d] = val;
                    else                 lvt[(h * 32 + d) * LVP + t] = val;
                }
        }
    }
    __syncthreads();

    // ---- phase 2: attention, 24 tasks over 8 waves ----
    const float* combw = comb + (size_t)(bwin & 63) * NH * 4096;
    unsigned short* pw = &lp[wave * 16 * LPP];

    #pragma unroll
    for (int ti = 0; ti < 3; ti++) {
        int task = wave + ti * 8;
        int h = task >> 2, mt = task & 3;
        int mbase = mt * 16;

        // S = Q K^T (d=32 -> single MFMA per key-tile)
        bf16x8 aq = *(const bf16x8*)&lq[(h * 64 + mbase + l15) * LQP + quad * 8];
        f32x4 sacc[4];
        #pragma unroll
        for (int j = 0; j < 4; j++) {
            bf16x8 bk = *(const bf16x8*)&lk[(h * 64 + j * 16 + l15) * LQP + quad * 8];
            f32x4 z = (f32x4){0.f, 0.f, 0.f, 0.f};
            sacc[j] = __builtin_amdgcn_mfma_f32_16x16x32_bf16(aq, bk, z, 0, 0, 0);
        }

        // softmax fp32: row = mbase+quad*4+r, col = j*16+l15
        const float* cb = combw + h * 4096;
        float s[4][4];
        #pragma unroll
        for (int j = 0; j < 4; j++)
            #pragma unroll
            for (int r = 0; r < 4; r++)
                s[j][r] = sacc[j][r] * SCALE + cb[(mbase + quad * 4 + r) * 64 + j * 16 + l15];
        float p[4][4], rsum[4];
        #pragma unroll
        for (int r = 0; r < 4; r++) {
            float m = fmaxf(fmaxf(s[0][r], s[1][r]), fmaxf(s[2][r], s[3][r]));
            for (int o = 1; o < 16; o <<= 1) m = fmaxf(m, __shfl_xor(m, o, 64));
            #pragma unroll
            for (int j = 0; j < 4; j++) p[j][r] = __expf(s[j][r] - m);
            float su = p[0][r] + p[1][r] + p[2][r] + p[3][r];
            for (int o = 1; o < 16; o <<= 1) su += __shfl_xor(su, o, 64);
            rsum[r] = su;
        }
        // P -> per-wave LDS slice (same-wave RAW; compiler inserts lgkmcnt)
        #pragma unroll
        for (int j = 0; j < 4; j++)
            #pragma unroll
            for (int r = 0; r < 4; r++)
                pw[(quad * 4 + r) * LPP + j * 16 + l15] = f2bf(p[j][r]);

        // O = P V
        f32x4 oacc[2];
        oacc[0] = (f32x4){0.f, 0.f, 0.f, 0.f};
        oacc[1] = (f32x4){0.f, 0.f, 0.f, 0.f};
        #pragma unroll
        for (int kstep = 0; kstep < 2; kstep++) {
            bf16x8 ap = *(const bf16x8*)&pw[l15 * LPP + kstep * 32 + quad * 8];
            #pragma unroll
            for (int n2 = 0; n2 < 2; n2++) {
                bf16x8 bv = *(const bf16x8*)&lvt[(h * 32 + n2 * 16 + l15) * LVP + kstep * 32 + quad * 8];
                oacc[n2] = __builtin_amdgcn_mfma_f32_16x16x32_bf16(ap, bv, oacc[n2], 0, 0, 0);
            }
        }
        // normalize + write Xa (into dead lx region)
        #pragma unroll
        for (int r = 0; r < 4; r++) {
            float inv = 1.0f / rsum[r];
            int t = mbase + quad * 4 + r;
            #pragma unroll
            for (int n2 = 0; n2 < 2; n2++)
                lx[t * LXP + h * 32 + n2 * 16 + l15] = f2bf(oacc[n2][r] * inv);
        }
    }

    // proj B-frags: issue before the barrier so loads overlap the wait
    bf16x8 pfr[3][6];
    #pragma unroll
    for (int nt = 0; nt < 3; nt++)
        #pragma unroll
        for (int ks = 0; ks < 6; ks++)
            pfr[nt][ks] = *(const bf16x8*)&Wproj[
                (size_t)(nbase + nt * 16 + l15) * 192 + ks * 32 + quad * 8];
    __syncthreads();

    // ---- phase 3: proj GEMM ----
    f32x4 pacc[2][3];
    #pragma unroll
    for (int mt = 0; mt < 2; mt++)
        #pragma unroll
        for (int nt = 0; nt < 3; nt++)
            pacc[mt][nt] = (f32x4){0.f, 0.f, 0.f, 0.f};

    #pragma unroll
    for (int ks = 0; ks < 6; ks++) {
        bf16x8 af[2];
        af[0] = *(const bf16x8*)&lx[(mh * 32 + l15) * LXP + ks * 32 + quad * 8];
        af[1] = *(const bf16x8*)&lx[(mh * 32 + 16 + l15) * LXP + ks * 32 + quad * 8];
        #pragma unroll
        for (int mt = 0; mt < 2; mt++)
            #pragma unroll
            for (int nt = 0; nt < 3; nt++)
                pacc[mt][nt] = __builtin_amdgcn_mfma_f32_16x16x32_bf16(
                    af[mt], pfr[nt][ks], pacc[mt][nt], 0, 0, 0);
    }

    #pragma unroll
    for (int nt = 0; nt < 3; nt++) {
        int cw = nbase + nt * 16 + l15;
        float bias = b_proj[cw];
        #pragma unroll
        for (int mt = 0; mt < 2; mt++)
            #pragma unroll
            for (int r = 0; r < 4; r++) {
                int t = mh * 32 + mt * 16 + quad * 4 + r;
                out[((size_t)bwin * NTOK + t) * WDIM + cw] = pacc[mt][nt][r] + bias;
            }
    }
}

// ---------------------------------------------------------------------------
extern "C" void kernel_launch(void* const* d_in, const int* in_sizes, int n_in,
                              void* d_out, int out_size, void* d_ws, size_t ws_size,
                              hipStream_t stream) {
    const float* x      = (const float*)d_in[0];
    const float* mask   = (const float*)d_in[1];
    const float* w_qkv  = (const float*)d_in[2];
    const float* b_qkv  = (const float*)d_in[3];
    const float* rpbt   = (const float*)d_in[4];
    const float* w_proj = (const float*)d_in[5];
    const float* b_proj = (const float*)d_in[6];
    float* out = (float*)d_out;

    const int B = in_sizes[0] / (NTOK * WDIM);   // 2048

    char* ws = (char*)d_ws;
    size_t o = 0;
    unsigned short* Wq = (unsigned short*)(ws + o); o += 576 * 192 * 2;
    unsigned short* Wp = (unsigned short*)(ws + o); o += 192 * 192 * 2;
    float* comb        = (float*)(ws + o);         o += (size_t)64 * NH * NTOK * NTOK * 4;

    const int prep_elems = 576 * 192 + 192 * 192 + 64 * NH * NTOK * NTOK;
    prep_kernel<<<(prep_elems + 255) / 256, 256, 0, stream>>>(
        w_qkv, w_proj, rpbt, mask, Wq, Wp, comb);
    fused_kernel<<<B, 512, 0, stream>>>(x, Wq, b_qkv, Wp, b_proj, comb, out);
}